// Round 5
// baseline (218.686 us; speedup 1.0000x reference)
//
#include <hip/hip_runtime.h>
#include <math.h>

#define E_CNT 1600000
#define HID 32
#define CH 16
#define NSEG 33                 // HID + 1 segments
#define TABF (2 * CH * NSEG)    // 1056 floats: At[c][m] then Bt[c][m], stride 33
#define TILE 256
#define NTILES (E_CNT / TILE)   // 6250
#define GRIDP 2048              // persistent blocks: exactly 8 per CU
#define ESTR 9                  // per-edge LDS row: sh[5], d, m, pad, pad (odd stride)

#define C_XY   1.0925484305920792f
#define C_Z2   0.31539156525252005f
#define C_X2Y2 0.5462742152960396f

typedef float f32x4 __attribute__((ext_vector_type(4)));   // native vec for nontemporal

// ---------------------------------------------------------------------------
// Precompute (one tiny launch): collapse the scalar-input MLP into
// piecewise-linear coefficients. radial[c](d) = A[m][c]*d + B[m][c],
// m = #{k : v_k < d}.  Transposed table: ws[0,32) breakpoints;
// ws[32 + c*NSEG + m] = At; ws[32 + 528 + c*NSEG + m] = Bt (stride 33, odd).
// ---------------------------------------------------------------------------
__global__ void precompute_kernel(const float* __restrict__ W1,
                                  const float* __restrict__ b1,
                                  const float* __restrict__ W2,
                                  const float* __restrict__ b2,
                                  float* __restrict__ ws) {
    __shared__ float s_v[HID], s_w1[HID], s_b1[HID];
    __shared__ int s_rank[HID];
    int tid = threadIdx.x;
    if (tid < HID) {
        float w = W1[tid], b = b1[tid];
        float v = 0.0f;
        if (w != 0.0f) v = fmaxf(-b / w, 0.0f);
        s_v[tid] = v; s_w1[tid] = w; s_b1[tid] = b;
    }
    __syncthreads();
    if (tid < HID) {
        float v = s_v[tid];
        int r = 0;
        for (int k = 0; k < HID; ++k) {
            float vk = s_v[k];
            r += (vk < v || (vk == v && k < tid)) ? 1 : 0;   // stable rank
        }
        s_rank[tid] = r;
        ws[tid] = v;
    }
    __syncthreads();
    if (tid < NSEG * CH) {
        int m = tid / CH;
        int c = tid % CH;
        float A = 0.0f, B = b2[c];
        for (int k = 0; k < HID; ++k) {
            float w = s_w1[k], b = s_b1[k];
            bool act;
            if (w > 0.0f)      act = (s_rank[k] < m);
            else if (w < 0.0f) act = (s_rank[k] >= m);
            else               act = (b > 0.0f);
            if (act) {
                float w2 = W2[k * CH + c];
                A = fmaf(w, w2, A);
                B = fmaf(b, w2, B);
            }
        }
        ws[32 + c * NSEG + m]             = A;   // transposed
        ws[32 + CH * NSEG + c * NSEG + m] = B;
    }
}

// ---------------------------------------------------------------------------
// Persistent-block edge kernel (fill-kernel-shaped store stream):
//  - grid = 2048 = 8 blocks/CU exactly; each block grid-strides ~3 tiles.
//  - ONE __syncthreads per block lifetime (sTab staging). After that each
//    WAVE is fully independent: phase 2 reads only its own 64 LDS rows.
//    Same-wave DS ordering makes the next tile's row overwrite safe.
//  - Cross-tile software pipeline: next tile's ei pair is issued at the top
//    of the current iteration and consumed a full iteration later, so the
//    ~900cy HBM miss hides under current-tile compute + stores.
//  - Phase 2: radial on the fly from the transposed table (<=2 channels per
//    float4), coalesced non-temporal 1KB/wave stores.
// ---------------------------------------------------------------------------
__global__ __launch_bounds__(TILE, 8) void edge_kernel(const float* __restrict__ pos,
                                                       const int* __restrict__ ei,
                                                       const float* __restrict__ ws,
                                                       float* __restrict__ out) {
    __shared__ float sTab[TABF];          // 4224 B
    __shared__ float sE[TILE * ESTR];     // 9216 B

    const int t = threadIdx.x;
    const int w = t >> 6;                 // wave id within block
    const int l = t & 63;                 // lane

    for (int q = t; q < TABF; q += TILE) sTab[q] = ws[32 + q];

    // Breakpoints: uniform constant-index -> scalar loads into SGPRs.
    float vbp[HID];
#pragma unroll
    for (int k = 0; k < HID; ++k) vbp[k] = ws[k];

    // Prologue: ei for this block's first tile (latency exposed once).
    int T = blockIdx.x;
    int cNi = ei[T * TILE + t];
    int cNj = ei[E_CNT + T * TILE + t];

    __syncthreads();                      // sTab ready -- the ONLY barrier

    float* row_w = &sE[t * ESTR];
    const float* rowbase = &sE[(w * 64) * ESTR];

    for (; T < NTILES; T += GRIDP) {
        // Issue next tile's ei immediately (hides under this whole iteration).
        int nNi = 0, nNj = 0;
        const int Tn = T + GRIDP;
        if (Tn < NTILES) {
            nNi = ei[Tn * TILE + t];
            nNj = ei[E_CNT + Tn * TILE + t];
        }

        // --- phase 1: gather (pos is L2/L3-hot) + geometry + segment ---
        const float* pi = pos + 3 * cNi;
        const float* pj = pos + 3 * cNj;
        const float rx = pi[0] - pj[0];
        const float ry = pi[1] - pj[1];
        const float rz = pi[2] - pj[2];
        const float d2   = fmaf(rx, rx, fmaf(ry, ry, rz * rz));
        const float dist = fmaxf(sqrtf(d2), 1e-8f);
        const float inv  = __builtin_amdgcn_rcpf(dist);
        const float x = rx * inv, y = ry * inv, z = rz * inv;
        row_w[0] = C_XY * x * y;
        row_w[1] = C_XY * y * z;
        row_w[2] = C_Z2 * fmaf(3.0f * z, z, -1.0f);
        row_w[3] = C_XY * x * z;
        row_w[4] = C_X2Y2 * (x * x - y * y);
        row_w[5] = dist;
        int m = 0;
#pragma unroll
        for (int k = 0; k < HID; ++k) m += (vbp[k] < dist) ? 1 : 0;
        row_w[6] = __int_as_float(m);

        // --- phase 2: per-wave coalesced NT store stream (no barrier) ---
        // lane reads only rows [w*64, w*64+64) -- written by its own wave.
        f32x4* ob = reinterpret_cast<f32x4*>(out)
                  + ((size_t)T * TILE + w * 64) * 20 + l;
#pragma unroll
        for (int it = 0; it < 20; ++it) {
            const int idx4 = l + 64 * it;          // [0,1280)
            const int el = idx4 / 20;              // local edge 0..63
            const int u  = idx4 - el * 20;
            const int p  = 4 * u;
            const int rA  =  p      / 5, si0 =  p      - 5 * rA;
            const int ri1 = (p + 1) / 5, si1 = (p + 1) - 5 * ri1;
            const int ri2 = (p + 2) / 5, si2 = (p + 2) - 5 * ri2;
            const int rB  = (p + 3) / 5, si3 = (p + 3) - 5 * rB;
            const float* row = rowbase + el * ESTR;
            const float d = row[5];
            const int   mm = __float_as_int(row[6]);
            const float rvA = fmaf(d, sTab[rA * NSEG + mm], sTab[CH * NSEG + rA * NSEG + mm]);
            const float rvB = fmaf(d, sTab[rB * NSEG + mm], sTab[CH * NSEG + rB * NSEG + mm]);
            f32x4 o;
            o.x = rvA * row[si0];
            o.y = (ri1 == rA ? rvA : rvB) * row[si1];
            o.z = (ri2 == rA ? rvA : rvB) * row[si2];
            o.w = rvB * row[si3];
            __builtin_nontemporal_store(o, ob + it * 64);
        }

        cNi = nNi; cNj = nNj;
    }
}

extern "C" void kernel_launch(void* const* d_in, const int* in_sizes, int n_in,
                              void* d_out, int out_size, void* d_ws, size_t ws_size,
                              hipStream_t stream) {
    const float* pos = (const float*)d_in[0];   // [50000,3]
    const float* W1  = (const float*)d_in[1];   // [1,32]
    const float* b1  = (const float*)d_in[2];   // [32]
    const float* W2  = (const float*)d_in[3];   // [32,16]
    const float* b2  = (const float*)d_in[4];   // [16]
    const int*   ei  = (const int*)d_in[5];     // [2,1600000]
    float* out = (float*)d_out;                 // [1600000,16,5]
    float* ws  = (float*)d_ws;

    precompute_kernel<<<1, 544, 0, stream>>>(W1, b1, W2, b2, ws);
    edge_kernel<<<GRIDP, TILE, 0, stream>>>(pos, ei, ws, out);
}

// Round 6
// 117.844 us; speedup vs baseline: 1.8557x; 1.8557x over previous
//
#include <hip/hip_runtime.h>
#include <math.h>

#define E_CNT 1600000
#define HID 32
#define CH 16
#define NSEG 33                 // HID + 1 segments
#define TABF (2 * CH * NSEG)    // 1056 floats: At[c][m] then Bt[c][m], stride 33
#define TILE 256
#define GRID (E_CNT / TILE)     // 6250 exactly
#define ESTR 9                  // per-edge LDS row: sh[5], d, m, pad, pad (odd stride)

#define C_XY   1.0925484305920792f
#define C_Z2   0.31539156525252005f
#define C_X2Y2 0.5462742152960396f

typedef float f32x4 __attribute__((ext_vector_type(4)));

// ---------------------------------------------------------------------------
// Precompute (one tiny launch): collapse the scalar-input MLP into
// piecewise-linear coefficients. radial[c](d) = A[m][c]*d + B[m][c],
// m = #{k : v_k < d}.  TRANSPOSED table layout for the edge kernel:
//   ws[0,32)                     breakpoints v_k
//   ws[32 + c*NSEG + m]          At  (channel-major, stride 33 = odd -> the
//   ws[32 + 528 + c*NSEG + m]    Bt   per-lane-m scalar reads spread banks)
// ---------------------------------------------------------------------------
__global__ void precompute_kernel(const float* __restrict__ W1,
                                  const float* __restrict__ b1,
                                  const float* __restrict__ W2,
                                  const float* __restrict__ b2,
                                  float* __restrict__ ws) {
    __shared__ float s_v[HID], s_w1[HID], s_b1[HID];
    __shared__ int s_rank[HID];
    int tid = threadIdx.x;
    if (tid < HID) {
        float w = W1[tid], b = b1[tid];
        float v = 0.0f;
        if (w != 0.0f) v = fmaxf(-b / w, 0.0f);
        s_v[tid] = v; s_w1[tid] = w; s_b1[tid] = b;
    }
    __syncthreads();
    if (tid < HID) {
        float v = s_v[tid];
        int r = 0;
        for (int k = 0; k < HID; ++k) {
            float vk = s_v[k];
            r += (vk < v || (vk == v && k < tid)) ? 1 : 0;   // stable rank
        }
        s_rank[tid] = r;
        ws[tid] = v;
    }
    __syncthreads();
    if (tid < NSEG * CH) {
        int m = tid / CH;
        int c = tid % CH;
        float A = 0.0f, B = b2[c];
        for (int k = 0; k < HID; ++k) {
            float w = s_w1[k], b = s_b1[k];
            bool act;
            if (w > 0.0f)      act = (s_rank[k] < m);
            else if (w < 0.0f) act = (s_rank[k] >= m);
            else               act = (b > 0.0f);
            if (act) {
                float w2 = W2[k * CH + c];
                A = fmaf(w, w2, A);
                B = fmaf(b, w2, B);
            }
        }
        ws[32 + c * NSEG + m]             = A;   // transposed
        ws[32 + CH * NSEG + c * NSEG + m] = B;
    }
}

// ---------------------------------------------------------------------------
// Main kernel == Round 4 (best: 113.3 us) with ONE change: regular stores
// instead of non-temporal (the 6.9 TB/s fill kernel uses regular stores;
// NT's L2-bypass may post writes with weaker combining at the HBM controller).
// Everything else identical: 13.4 KB LDS -> 8 blocks x 4 waves = 32 waves/CU,
// __launch_bounds__(256,8); phase 1 writes {sh[5],d,m}; phase 2 evaluates the
// <=2 needed radial channels on the fly from the transposed PWL table.
// ---------------------------------------------------------------------------
__global__ __launch_bounds__(TILE, 8) void edge_kernel(const float* __restrict__ pos,
                                                       const int* __restrict__ ei,
                                                       const float* __restrict__ ws,
                                                       float* __restrict__ out) {
    __shared__ float sTab[TABF];          // 4224 B
    __shared__ float sE[TILE * ESTR];     // 9216 B

    const int t = threadIdx.x;
    const int e = blockIdx.x * TILE + t;

    // Issue the gather-chain loads as early as possible.
    const int ni = ei[e];
    const int nj = ei[E_CNT + e];

    for (int q = t; q < TABF; q += TILE) sTab[q] = ws[32 + q];

    // Breakpoints: uniform constant-index -> scalar loads into SGPRs.
    float vbp[HID];
#pragma unroll
    for (int k = 0; k < HID; ++k) vbp[k] = ws[k];

    // dependent gather (ni/nj long since returned)
    const float* pi = pos + 3 * ni;
    const float* pj = pos + 3 * nj;
    const float rx = pi[0] - pj[0];
    const float ry = pi[1] - pj[1];
    const float rz = pi[2] - pj[2];

    const float d2   = fmaf(rx, rx, fmaf(ry, ry, rz * rz));
    const float dist = fmaxf(sqrtf(d2), 1e-8f);
    const float inv  = __builtin_amdgcn_rcpf(dist);
    const float x = rx * inv, y = ry * inv, z = rz * inv;

    float* row_w = &sE[t * ESTR];
    row_w[0] = C_XY * x * y;
    row_w[1] = C_XY * y * z;
    row_w[2] = C_Z2 * fmaf(3.0f * z, z, -1.0f);
    row_w[3] = C_XY * x * z;
    row_w[4] = C_X2Y2 * (x * x - y * y);
    row_w[5] = dist;

    int m = 0;                               // segment index for my edge
#pragma unroll
    for (int k = 0; k < HID; ++k) m += (vbp[k] < dist) ? 1 : 0;
    row_w[6] = __int_as_float(m);

    __syncthreads();                         // sTab + sE ready

    // --- phase 2: coalesced float4 store stream (regular stores) ---
    // float4 index idx4 = t + 256*it in [0,5120): edge el = idx4/20,
    // word p = (idx4%20)*4; channels needed: rA=p/5, rB=(p+3)/5 (<=2 distinct).
    f32x4* ob = reinterpret_cast<f32x4*>(out) + (size_t)blockIdx.x * (TILE * 20) + t;
#pragma unroll
    for (int it = 0; it < 20; ++it) {
        const int idx4 = t + TILE * it;
        const int el = idx4 / 20;
        const int u  = idx4 - el * 20;
        const int p  = 4 * u;
        const int rA  =  p      / 5;
        const int ri1 = (p + 1) / 5;
        const int ri2 = (p + 2) / 5;
        const int rB  = (p + 3) / 5;
        const int si0 =  p      - 5 * rA;
        const int si1 = (p + 1) - 5 * ri1;
        const int si2 = (p + 2) - 5 * ri2;
        const int si3 = (p + 3) - 5 * rB;
        const float* row = &sE[el * ESTR];
        const float d = row[5];
        const int   mm = __float_as_int(row[6]);
        const float rvA = fmaf(d, sTab[rA * NSEG + mm], sTab[CH * NSEG + rA * NSEG + mm]);
        const float rvB = fmaf(d, sTab[rB * NSEG + mm], sTab[CH * NSEG + rB * NSEG + mm]);
        f32x4 o;
        o.x = rvA * row[si0];
        o.y = (ri1 == rA ? rvA : rvB) * row[si1];
        o.z = (ri2 == rA ? rvA : rvB) * row[si2];
        o.w = rvB * row[si3];
        ob[it * TILE] = o;                   // regular store (through L2)
    }
}

extern "C" void kernel_launch(void* const* d_in, const int* in_sizes, int n_in,
                              void* d_out, int out_size, void* d_ws, size_t ws_size,
                              hipStream_t stream) {
    const float* pos = (const float*)d_in[0];   // [50000,3]
    const float* W1  = (const float*)d_in[1];   // [1,32]
    const float* b1  = (const float*)d_in[2];   // [32]
    const float* W2  = (const float*)d_in[3];   // [32,16]
    const float* b2  = (const float*)d_in[4];   // [16]
    const int*   ei  = (const int*)d_in[5];     // [2,1600000]
    float* out = (float*)d_out;                 // [1600000,16,5]
    float* ws  = (float*)d_ws;

    precompute_kernel<<<1, 544, 0, stream>>>(W1, b1, W2, b2, ws);
    edge_kernel<<<GRID, TILE, 0, stream>>>(pos, ei, ws, out);
}

// Round 7
// 112.921 us; speedup vs baseline: 1.9366x; 1.0436x over previous
//
#include <hip/hip_runtime.h>
#include <math.h>

#define E_CNT 1600000
#define HID 32
#define CH 16
#define NSEG 33                 // HID + 1 segments
#define TABF (2 * CH * NSEG)    // 1056 floats: At[c][m] then Bt[c][m], stride 33
#define TILE 128                // 2 waves per block -> 16 block slots/CU
#define GRID (E_CNT / TILE)     // 12500 exactly
#define ESTR 9                  // per-edge LDS row: sh[5], d, m, pad, pad (odd stride)

#define C_XY   1.0925484305920792f
#define C_Z2   0.31539156525252005f
#define C_X2Y2 0.5462742152960396f

typedef float f32x4 __attribute__((ext_vector_type(4)));

// ---------------------------------------------------------------------------
// Precompute (one tiny launch): collapse the scalar-input MLP into
// piecewise-linear coefficients. radial[c](d) = A[m][c]*d + B[m][c],
// m = #{k : v_k < d}.  TRANSPOSED table layout for the edge kernel:
//   ws[0,32)                     breakpoints v_k
//   ws[32 + c*NSEG + m]          At  (channel-major, stride 33 = odd -> the
//   ws[32 + 528 + c*NSEG + m]    Bt   per-lane-m scalar reads spread banks)
// ---------------------------------------------------------------------------
__global__ void precompute_kernel(const float* __restrict__ W1,
                                  const float* __restrict__ b1,
                                  const float* __restrict__ W2,
                                  const float* __restrict__ b2,
                                  float* __restrict__ ws) {
    __shared__ float s_v[HID], s_w1[HID], s_b1[HID];
    __shared__ int s_rank[HID];
    int tid = threadIdx.x;
    if (tid < HID) {
        float w = W1[tid], b = b1[tid];
        float v = 0.0f;
        if (w != 0.0f) v = fmaxf(-b / w, 0.0f);
        s_v[tid] = v; s_w1[tid] = w; s_b1[tid] = b;
    }
    __syncthreads();
    if (tid < HID) {
        float v = s_v[tid];
        int r = 0;
        for (int k = 0; k < HID; ++k) {
            float vk = s_v[k];
            r += (vk < v || (vk == v && k < tid)) ? 1 : 0;   // stable rank
        }
        s_rank[tid] = r;
        ws[tid] = v;
    }
    __syncthreads();
    if (tid < NSEG * CH) {
        int m = tid / CH;
        int c = tid % CH;
        float A = 0.0f, B = b2[c];
        for (int k = 0; k < HID; ++k) {
            float w = s_w1[k], b = s_b1[k];
            bool act;
            if (w > 0.0f)      act = (s_rank[k] < m);
            else if (w < 0.0f) act = (s_rank[k] >= m);
            else               act = (b > 0.0f);
            if (act) {
                float w2 = W2[k * CH + c];
                A = fmaf(w, w2, A);
                B = fmaf(b, w2, B);
            }
        }
        ws[32 + c * NSEG + m]             = A;   // transposed
        ws[32 + CH * NSEG + c * NSEG + m] = B;
    }
}

// ---------------------------------------------------------------------------
// Round 7: Round 4 (113.3 us, NT stores kept) + store-silence de-alignment:
//  - TILE=128 (2 waves), 16 block slots/CU (8.8 KB LDS), still 32 waves/CU.
//    2x the independently-churning slots -> silent phase-1 windows across a
//    CU stagger instead of aligning at generation turnover.
//  - NO mid-block barrier: phase 2 is per-wave (each wave reads only its own
//    64 LDS rows, R5-validated indexing); in-wave ordering via
//    s_waitcnt lgkmcnt(0). The slowest gather no longer stalls sibling waves.
//  - Only remaining __syncthreads is the one-time sTab staging.
// ---------------------------------------------------------------------------
__global__ __launch_bounds__(TILE, 8) void edge_kernel(const float* __restrict__ pos,
                                                       const int* __restrict__ ei,
                                                       const float* __restrict__ ws,
                                                       float* __restrict__ out) {
    __shared__ float sTab[TABF];          // 4224 B
    __shared__ float sE[TILE * ESTR];     // 4608 B

    const int t = threadIdx.x;
    const int w = t >> 6;                 // wave id within block (0..1)
    const int l = t & 63;                 // lane
    const int e = blockIdx.x * TILE + t;

    // Issue the gather-chain loads as early as possible.
    const int ni = ei[e];
    const int nj = ei[E_CNT + e];

    for (int q = t; q < TABF; q += TILE) sTab[q] = ws[32 + q];

    // Breakpoints: uniform constant-index -> scalar loads into SGPRs.
    float vbp[HID];
#pragma unroll
    for (int k = 0; k < HID; ++k) vbp[k] = ws[k];

    // dependent gather (ni/nj long since returned)
    const float* pi = pos + 3 * ni;
    const float* pj = pos + 3 * nj;
    const float rx = pi[0] - pj[0];
    const float ry = pi[1] - pj[1];
    const float rz = pi[2] - pj[2];

    const float d2   = fmaf(rx, rx, fmaf(ry, ry, rz * rz));
    const float dist = fmaxf(sqrtf(d2), 1e-8f);
    const float inv  = __builtin_amdgcn_rcpf(dist);
    const float x = rx * inv, y = ry * inv, z = rz * inv;

    __syncthreads();                         // sTab ready (one-time)

    float* row_w = &sE[t * ESTR];
    row_w[0] = C_XY * x * y;
    row_w[1] = C_XY * y * z;
    row_w[2] = C_Z2 * fmaf(3.0f * z, z, -1.0f);
    row_w[3] = C_XY * x * z;
    row_w[4] = C_X2Y2 * (x * x - y * y);
    row_w[5] = dist;

    int m = 0;                               // segment index for my edge
#pragma unroll
    for (int k = 0; k < HID; ++k) m += (vbp[k] < dist) ? 1 : 0;
    row_w[6] = __int_as_float(m);

    // In-wave LDS ordering: my wave's 64 rows are complete once lgkmcnt==0.
    // (LDS is physically shared per CU; same-wave cross-lane visibility needs
    // only write completion, not a block barrier.)
    asm volatile("s_waitcnt lgkmcnt(0)" ::: "memory");

    // --- phase 2: per-wave coalesced NT float4 store stream ---
    // idx4 = l + 64*it in [0,1280): local edge el = idx4/20 (0..63 within my
    // wave's rows), word p = (idx4%20)*4; channels rA=p/5, rB=(p+3)/5.
    const float* rowbase = &sE[(w * 64) * ESTR];
    f32x4* ob = reinterpret_cast<f32x4*>(out)
              + ((size_t)blockIdx.x * TILE + w * 64) * 20 + l;
#pragma unroll
    for (int it = 0; it < 20; ++it) {
        const int idx4 = l + 64 * it;
        const int el = idx4 / 20;
        const int u  = idx4 - el * 20;
        const int p  = 4 * u;
        const int rA  =  p      / 5, si0 =  p      - 5 * rA;
        const int ri1 = (p + 1) / 5, si1 = (p + 1) - 5 * ri1;
        const int ri2 = (p + 2) / 5, si2 = (p + 2) - 5 * ri2;
        const int rB  = (p + 3) / 5, si3 = (p + 3) - 5 * rB;
        const float* row = rowbase + el * ESTR;
        const float d = row[5];
        const int   mm = __float_as_int(row[6]);
        const float rvA = fmaf(d, sTab[rA * NSEG + mm], sTab[CH * NSEG + rA * NSEG + mm]);
        const float rvB = fmaf(d, sTab[rB * NSEG + mm], sTab[CH * NSEG + rB * NSEG + mm]);
        f32x4 o;
        o.x = rvA * row[si0];
        o.y = (ri1 == rA ? rvA : rvB) * row[si1];
        o.z = (ri2 == rA ? rvA : rvB) * row[si2];
        o.w = rvB * row[si3];
        __builtin_nontemporal_store(o, ob + it * 64);
    }
}

extern "C" void kernel_launch(void* const* d_in, const int* in_sizes, int n_in,
                              void* d_out, int out_size, void* d_ws, size_t ws_size,
                              hipStream_t stream) {
    const float* pos = (const float*)d_in[0];   // [50000,3]
    const float* W1  = (const float*)d_in[1];   // [1,32]
    const float* b1  = (const float*)d_in[2];   // [32]
    const float* W2  = (const float*)d_in[3];   // [32,16]
    const float* b2  = (const float*)d_in[4];   // [16]
    const int*   ei  = (const int*)d_in[5];     // [2,1600000]
    float* out = (float*)d_out;                 // [1600000,16,5]
    float* ws  = (float*)d_ws;

    precompute_kernel<<<1, 544, 0, stream>>>(W1, b1, W2, b2, ws);
    edge_kernel<<<GRID, TILE, 0, stream>>>(pos, ei, ws, out);
}